// Round 9
// baseline (8086.275 us; speedup 1.0000x reference)
//
#include <hip/hip_runtime.h>
#include <cstdint>
#include <cstddef>

// ---------------------------------------------------------------------------
// QRNN 2-bit forward, exact ternary-integer formulation.
// flags[0]=1 -> floats are f32 (else bf16); flags[1]=1 -> text is int64.
// Ternary vectors (len 1024) bit-packed as 32 u64: [2i]=plus, [2i+1]=nonzero.
// As uint4 i: (p.lo, p.hi, z.lo, z.hi) for elements 64i..64i+63.
// dot: both=hz&wz; neg=both&(hp^wp); k=popc(both)-2*popc(neg)
// Decision v = k*0.1+bias vs +-0.5 is monotone in k -> precomputed integer
// thresholds kp/km reproduce the f64 predicate bit-exactly.
//
// R-pipeline (k_pipe, 96 blocks = 32 A + 32 B + 32 C, 2 BATCHES PER BLOCK):
//   A = layer-0 recur (produces x_t), B = layer-1 input bit-GEMM (x_t -> n_t,
//   in-place into nbuf), C = layer-1 recur (consumes n_t).
// Fenceless handoff (R2, validated): all cross-stage data stores/loads are
// RELAXED+AGENT (sc0 sc1 -> write/read-through the IC, never dirty in L2 =>
// no wbl2). Pair-level flags are RELAXED agent stores issued AFTER
// __syncthreads() (the barrier's implicit vmcnt(0) drain => all waves' IC
// stores visible first). Consumer data loads are control-dependent on
// observed flag values => ordered without acquire fences. Same-address flag
// stores separated by barriers. Dependency graph acyclic (A never waits);
// 96 blocks x 16 waves @ 1 block/CU co-resident on 256 CUs => no deadlock.
//
// R9 (this round): WEIGHT STREAM AMORTIZATION, not residency.
// Residency verdict after 6 failed rounds (R4-R8): the backend refuses to
// materialize the 64 loop-invariant weight words at ANY hint (VGPR_Count
// pinned at 48/64; asm pins spill to scratch instead). Accept the re-stream
// and fix its REAL cost: it is per-XCD L2-BW-bound, not per-CU.
//   R0 (64 CUs):  8 CU/XCD x 256 KB/step = 2 MB/XCD ~1140cy -> not bound.
//   R2/R3 (192):  24 CU/XCD = 6 MB/XCD ~3400cy -> L2-BOUND (the 5520cy
//   invariant step that no VALU/LDS change could move).
// Weights are batch-independent => 2 batches/block: one L2 weight quad
// feeds two dots. 96 blocks: 12 CU/XCD x 256 KB = 3 MB ~1700cy < dual-dot
// VALU ~3000-3400cy => VALU-bound at a LOWER step; 64 batches still done
// in 512 steps. Live set ~35 regs fits the 64-VGPR allocation naturally.
// ---------------------------------------------------------------------------

#define FLAG_STRIDE 16  // one flag per 64 B to avoid line contention

static __device__ __forceinline__ float bf2f(unsigned short b) {
  return __uint_as_float(((unsigned)b) << 16);
}
static __device__ __forceinline__ unsigned short f2bf(float f) {
  unsigned u = __float_as_uint(f);
  u = (u + 0x7FFFu + ((u >> 16) & 1u)) >> 16;  // RNE
  return (unsigned short)u;
}
static __device__ __forceinline__ float loadw(const void* p, size_t i, int isf32) {
  return isf32 ? ((const float*)p)[i] : bf2f(((const unsigned short*)p)[i]);
}

__global__ __launch_bounds__(256) void k_detect(const unsigned short* __restrict__ embu,
                                                const int* __restrict__ text,
                                                int* __restrict__ flags) {
  int i = blockIdx.x * 256 + threadIdx.x;  // 65536 u16 samples: valid in either layout
  unsigned e = (embu[i] >> 7) & 0xFFu;     // bf16-view exponent field
  unsigned long long b = __ballot(e >= 127u);
  if ((threadIdx.x & 63) == 0 && b) atomicOr(&flags[0], 1);
  if (blockIdx.x == 0 && threadIdx.x == 0) {
    int allz = 1;
    for (int j = 0; j < 32; j++)
      if (text[2 * j + 1] != 0) allz = 0;   // first 256 B: valid in either layout
    flags[1] = allz;
  }
}

// vectorized max|emb|
__global__ __launch_bounds__(256) void k_maxabs(const uint4* __restrict__ w,
                                                const int* __restrict__ flags,
                                                unsigned* __restrict__ out) {
  int isf32 = flags[0];
  int n16 = isf32 ? 7680000 : 3840000;  // 30720000 elems / (4 or 8 per uint4)
  float mf = 0.f;
  unsigned mb = 0;
  int i = blockIdx.x * blockDim.x + threadIdx.x;
  int stride = gridDim.x * blockDim.x;
  if (isf32) {
    for (; i < n16; i += stride) {
      uint4 v = w[i];
      mf = fmaxf(mf, fabsf(__uint_as_float(v.x)));
      mf = fmaxf(mf, fabsf(__uint_as_float(v.y)));
      mf = fmaxf(mf, fabsf(__uint_as_float(v.z)));
      mf = fmaxf(mf, fabsf(__uint_as_float(v.w)));
    }
  } else {
    for (; i < n16; i += stride) {
      uint4 v = w[i];
      unsigned a;
      a = v.x & 0x7FFF7FFFu; mb = max(mb, a & 0xFFFFu); mb = max(mb, a >> 16);
      a = v.y & 0x7FFF7FFFu; mb = max(mb, a & 0xFFFFu); mb = max(mb, a >> 16);
      a = v.z & 0x7FFF7FFFu; mb = max(mb, a & 0xFFFFu); mb = max(mb, a >> 16);
      a = v.w & 0x7FFF7FFFu; mb = max(mb, a & 0xFFFFu); mb = max(mb, a >> 16);
    }
    mf = bf2f((unsigned short)mb);
  }
  for (int off = 32; off > 0; off >>= 1) mf = fmaxf(mf, __shfl_down(mf, off));
  __shared__ float red[4];
  if ((threadIdx.x & 63) == 0) red[threadIdx.x >> 6] = mf;
  __syncthreads();
  if (threadIdx.x == 0) {
    float b = fmaxf(fmaxf(red[0], red[1]), fmaxf(red[2], red[3]));
    atomicMax(out, __float_as_uint(b));  // b >= 0: bit pattern order-monotone
  }
}

__global__ __launch_bounds__(1024) void k_tern_rows(
    const void* __restrict__ Wih, const void* __restrict__ Whh,
    const void* __restrict__ fcw, const int* __restrict__ flags,
    unsigned long long* __restrict__ wim, unsigned long long* __restrict__ whm,
    unsigned long long* __restrict__ fcm) {
  int isf32 = flags[0];
  int b = blockIdx.x;  // 0..4099
  const void* src;
  size_t rowoff;
  unsigned long long* dst;
  if (b < 2048)      { src = Wih; rowoff = (size_t)b * 1024; dst = wim + (size_t)b * 32; }
  else if (b < 4096) { int r = b - 2048; src = Whh; rowoff = (size_t)r * 1024; dst = whm + (size_t)r * 32; }
  else               { int r = b - 4096; src = fcw; rowoff = (size_t)r * 1024; dst = fcm + (size_t)r * 32; }
  double w = (double)loadw(src, rowoff + threadIdx.x, isf32);
  unsigned long long bp = __ballot(w > 0.05);   // THR*W_SCALE, exact f64
  unsigned long long bm = __ballot(w < -0.05);
  if ((threadIdx.x & 63) == 0) {
    int wv = threadIdx.x >> 6;
    dst[2 * wv] = bp;
    dst[2 * wv + 1] = bp | bm;
  }
}

__global__ __launch_bounds__(1024) void k_embed(const int* __restrict__ text,
    const void* __restrict__ emb, const int* __restrict__ flags,
    const unsigned* __restrict__ mab, unsigned long long* __restrict__ x0) {
  int isf32 = flags[0], i64 = flags[1];
  int bt = blockIdx.x;
  long long tok = i64 ? ((const long long*)text)[bt] : (long long)text[bt];
  double ma = (double)__uint_as_float(*mab);
  float s = (float)exp2(ceil(log2(ma)));           // pow-2 scale (int_max = 1)
  float inv_s = 1.0f / s;                          // exact (pow-2)
  float w = loadw(emb, (size_t)tok * 1024 + threadIdx.x, isf32);
  float q = rintf(w * inv_s);                      // exact mul, half-even
  q = fminf(fmaxf(q, -2.0f), 1.0f);                // clip [-2, 1] (bw = 2)
  float val = q * s;                               // exact
  int code = (val > 0.5f) ? 1 : ((val < -0.5f) ? -1 : 0);
  unsigned long long bp = __ballot(code == 1);
  unsigned long long bm = __ballot(code == -1);
  if ((threadIdx.x & 63) == 0) {
    int wv = threadIdx.x >> 6;
    x0[(size_t)bt * 32 + 2 * wv] = bp;
    x0[(size_t)bt * 32 + 2 * wv + 1] = bp | bm;
  }
}

// ---- bit-GEMM (layer-0 pre-pass): n[bt][r] = <x_row[bt], Wi_row[r]> -------
__global__ __launch_bounds__(256, 4) void k_bitgemm(const unsigned long long* __restrict__ xm,
    const unsigned long long* __restrict__ wim, short* __restrict__ nbuf) {
  __shared__ __align__(16) uint4 lx[64 * 16];  // [bt][i] = (p.lo,p.hi,z.lo,z.hi)
  __shared__ unsigned any[64];
  int tid = threadIdx.x;
  int bt0 = blockIdx.x * 64;
  int r = blockIdx.y * 256 + tid;
  unsigned wplo[16], wphi[16], wzlo[16], wzhi[16];
  const uint4* wrow = (const uint4*)(wim + (size_t)r * 32);
#pragma unroll
  for (int i = 0; i < 16; i++) {
    uint4 w4 = wrow[i];
    wplo[i] = w4.x; wphi[i] = w4.y; wzlo[i] = w4.z; wzhi[i] = w4.w;
  }
  if (tid < 64) any[tid] = 0;
  __syncthreads();
  unsigned accor = 0;
#pragma unroll
  for (int i = 0; i < 4; i++) {
    int idx = tid * 4 + i;  // 0..1023 uint4 slots, straight copy
    uint4 v = ((const uint4*)(xm + (size_t)bt0 * 32))[idx];
    lx[idx] = v;
    accor |= v.z | v.w;  // nonzero-mask halves
  }
  if (accor) atomicOr(&any[tid >> 2], 1u);  // 4 threads per bt row
  __syncthreads();
  for (int bt = 0; bt < 64; bt++) {
    int k = 0;
    if (any[bt]) {
      const uint4* hx = lx + bt * 16;
      int sb = 0, sn = 0;
#pragma unroll
      for (int i = 0; i < 16; i++) {
        uint4 h = hx[i];  // broadcast ds_read_b128
        unsigned blo = h.z & wzlo[i];
        unsigned bhi = h.w & wzhi[i];
        unsigned nlo = (h.x ^ wplo[i]) & blo;
        unsigned nhi = (h.y ^ wphi[i]) & bhi;
        sb += __popc(blo) + __popc(bhi);
        sn += __popc(nlo) + __popc(nhi);
      }
      k = sb - 2 * sn;
    }
    nbuf[(size_t)(bt0 + bt) * 1024 + r] = (short)k;
  }
}

// ---- fused 3-stage pipeline, 2 batches/block ------------------------------

static __device__ __forceinline__ int ldflag(const int* p) {
  return __hip_atomic_load(p, __ATOMIC_RELAXED, __HIP_MEMORY_SCOPE_AGENT);
}
static __device__ __forceinline__ void stflag(int* p, int v) {
  __hip_atomic_store(p, v, __ATOMIC_RELAXED, __HIP_MEMORY_SCOPE_AGENT);
}
static __device__ __forceinline__ unsigned long long ldu64(const unsigned long long* p) {
  return __hip_atomic_load(p, __ATOMIC_RELAXED, __HIP_MEMORY_SCOPE_AGENT);
}
static __device__ __forceinline__ int lds16(const short* p) {
  return (int)__hip_atomic_load(p, __ATOMIC_RELAXED, __HIP_MEMORY_SCOPE_AGENT);
}
static __device__ __forceinline__ void sts16(short* p, short v) {
  __hip_atomic_store(p, v, __ATOMIC_RELAXED, __HIP_MEMORY_SCOPE_AGENT);
}
static __device__ __forceinline__ void stu64(unsigned long long* p, unsigned long long v) {
  __hip_atomic_store(p, v, __ATOMIC_RELAXED, __HIP_MEMORY_SCOPE_AGENT);
}

// dual-batch bit-dot: ONE weight quad load (L2) feeds both batches' dots.
// Split accumulators; ~35 live regs -- fits the 64-VGPR allocation.
#define DOT16X2(H0, H1, K0, K1, N0, N1)                                    \
  int K0, K1;                                                              \
  do {                                                                     \
    int s0a = 0, s0b = 0, m0a = 0, m0b = 0;                                \
    int s1a = 0, s1b = 0, m1a = 0, m1b = 0;                                \
    _Pragma("unroll")                                                      \
    for (int _i = 0; _i < 16; _i++) {                                      \
      uint4 _w = wrow[_i];         /* one L2 load per quad */              \
      uint4 _h0 = (H0)[_i];        /* broadcast ds_read_b128 */            \
      uint4 _h1 = (H1)[_i];                                                \
      unsigned _b, _c, _d, _e;                                             \
      _b = _h0.z & _w.z; _c = _h0.w & _w.w;                                \
      _d = (_h0.x ^ _w.x) & _b; _e = (_h0.y ^ _w.y) & _c;                  \
      if (_i & 1) { s0b += __popc(_b); s0b += __popc(_c);                  \
                    m0b += __popc(_d); m0b += __popc(_e); }                \
      else        { s0a += __popc(_b); s0a += __popc(_c);                  \
                    m0a += __popc(_d); m0a += __popc(_e); }                \
      _b = _h1.z & _w.z; _c = _h1.w & _w.w;                                \
      _d = (_h1.x ^ _w.x) & _b; _e = (_h1.y ^ _w.y) & _c;                  \
      if (_i & 1) { s1b += __popc(_b); s1b += __popc(_c);                  \
                    m1b += __popc(_d); m1b += __popc(_e); }                \
      else        { s1a += __popc(_b); s1a += __popc(_c);                  \
                    m1a += __popc(_d); m1a += __popc(_e); }                \
    }                                                                      \
    K0 = (N0) + (s0a + s0b) - 2 * (m0a + m0b);                             \
    K1 = (N1) + (s1a + s1b) - 2 * (m1a + m1b);                             \
  } while (0)

// integer thresholds reproducing the f64 predicate for one bias
static __device__ __forceinline__ void mk_thresh(double bias, int& kp, int& km) {
  kp = (int)ceil((0.5 - bias) * 10.0);
  while ((double)kp * 0.1 + bias <= 0.5) kp++;
  while ((double)(kp - 1) * 0.1 + bias > 0.5) kp--;
  km = (int)floor((-0.5 - bias) * 10.0);
  while ((double)km * 0.1 + bias >= -0.5) km--;
  while ((double)(km + 1) * 0.1 + bias < -0.5) km++;
}

// ROLE 0 = layer-0 recur (producer of x_t); ROLE 2 = layer-1 recur (consumer)
// Handles batches b0=2*pair, b1=b0+1 (shared weights, shared biases).
template <int ROLE>
static __device__ __forceinline__ void recur2(
    uint4 (*shb)[2][16],  // [bat][buf][16]
    const short* nbuf,
    const unsigned long long* __restrict__ whm,
    const void* __restrict__ bih, const void* __restrict__ bhh,
    int isf32, int layer, int pair, int r,
    unsigned long long* x0base,            // ROLE 0 only (else null)
    int* flagsA, int* flagsB,
    unsigned long long* __restrict__ hidm) {
  int b0 = 2 * pair, b1 = b0 + 1;
  const uint4* wrow = (const uint4*)(whm + (size_t)(layer * 1024 + r) * 32);
  size_t boff = (size_t)layer * 1024 + r;
  double bias = (double)loadw(bih, boff, isf32) + (double)loadw(bhh, boff, isf32);
  int kp, km;
  mk_thresh(bias, kp, km);

  if (r < 128) ((unsigned long long*)shb)[r] = 0;  // zero all bufs, both bats
  const short* nrow0 = nbuf + (size_t)b0 * 512 * 1024 + r;
  const short* nrow1 = nbuf + (size_t)b1 * 512 * 1024 + r;
  unsigned long long* xrow0 = x0base ? x0base + (size_t)b0 * 512 * 32 : (unsigned long long*)0;
  unsigned long long* xrow1 = x0base ? x0base + (size_t)b1 * 512 * 32 : (unsigned long long*)0;
  int wv = r >> 6;
  bool l0 = (r & 63) == 0;
  int fb = 0;   // ROLE 2: cached flagsB[pair]
  int* flagsAp = flagsA + pair * FLAG_STRIDE;
  int* flagsBp = flagsB + pair * FLAG_STRIDE;
  int n00, n01, n10, n11;  // n{bat}{slot t, t+1}
  if (ROLE == 0) {  // pre-pass data: plain loads fine
    n00 = (int)nrow0[0]; n01 = (int)nrow0[1024];
    n10 = (int)nrow1[0]; n11 = (int)nrow1[1024];
  } else {
    while ((fb = ldflag(flagsBp)) < 2) {}
    // data loads control-dependent on flag value => ordered, no acquire
    n00 = lds16(nrow0); n01 = lds16(nrow0 + 1024);
    n10 = lds16(nrow1); n11 = lds16(nrow1 + 1024);
  }
  __syncthreads();
  int pb = 0;
  unsigned long long p0lo = 0, p0hi = 0, p1lo = 0, p1hi = 0;  // deferred x
  for (int t = 0; t < 512; t++) {
    // ---- top of step: issue ALL memory ops (acks covered by the dot) ----
    if (ROLE == 0 && l0 && t > 0) {  // deferred stores of x_{t-1}, both bats
      unsigned long long* xp0 = xrow0 + (size_t)(t - 1) * 32;
      unsigned long long* xp1 = xrow1 + (size_t)(t - 1) * 32;
      stu64(xp0 + 2 * wv, p0lo); stu64(xp0 + 2 * wv + 1, p0hi);
      stu64(xp1 + 2 * wv, p1lo); stu64(xp1 + 2 * wv + 1, p1hi);
    }
    int n02 = 0, n12 = 0;
    bool got = true;
    if (t < 510) {  // distance-2 prefetch of n_{t+2}, both bats
      if (ROLE == 0) {
        n02 = (int)nrow0[(size_t)(t + 2) * 1024];
        n12 = (int)nrow1[(size_t)(t + 2) * 1024];
      } else {
        if (fb < t + 3) fb = ldflag(flagsBp);
        got = (fb >= t + 3);
        if (got) {
          n02 = lds16(nrow0 + (size_t)(t + 2) * 1024);
          n12 = lds16(nrow1 + (size_t)(t + 2) * 1024);
        }
      }
    }
    // ---- dual dot over current h0, h1 ----
    const uint4* H0 = shb[0][pb];
    const uint4* H1 = shb[1][pb];
    DOT16X2(H0, H1, k0, k1, n00, n10);
    unsigned long long bp0 = __ballot(k0 >= kp);
    unsigned long long bz0 = bp0 | __ballot(k0 <= km);
    unsigned long long bp1 = __ballot(k1 >= kp);
    unsigned long long bz1 = bp1 | __ballot(k1 <= km);
    if (l0) {
      uint4 o0, o1;
      o0.x = (unsigned)bp0; o0.y = (unsigned)(bp0 >> 32);
      o0.z = (unsigned)bz0; o0.w = (unsigned)(bz0 >> 32);
      o1.x = (unsigned)bp1; o1.y = (unsigned)(bp1 >> 32);
      o1.z = (unsigned)bz1; o1.w = (unsigned)(bz1 >> 32);
      shb[0][pb ^ 1][wv] = o0;
      shb[1][pb ^ 1][wv] = o1;
      p0lo = bp0; p0hi = bz0; p1lo = bp1; p1hi = bz1;  // defer global store
    }
    if (ROLE == 2 && t < 510 && !got) {  // cold path: pipeline fill only
      while ((fb = ldflag(flagsBp)) < t + 3) {}
      n02 = lds16(nrow0 + (size_t)(t + 2) * 1024);
      n12 = lds16(nrow1 + (size_t)(t + 2) * 1024);
    }
    __syncthreads();  // implicit vmcnt(0)+lgkmcnt(0): stores/loads drained
    // publish AFTER barrier: all waves' x[<=t-1] stores globally visible.
    if (ROLE == 0 && r == 0 && t > 0) stflag(flagsAp, t);
    pb ^= 1;
    n00 = n01; n01 = n02;
    n10 = n11; n11 = n12;
  }
  if (ROLE == 0) {  // commit x[511] both bats, then final publish
    if (l0) {
      unsigned long long* xp0 = xrow0 + (size_t)511 * 32;
      unsigned long long* xp1 = xrow1 + (size_t)511 * 32;
      stu64(xp0 + 2 * wv, p0lo); stu64(xp0 + 2 * wv + 1, p0hi);
      stu64(xp1 + 2 * wv, p1lo); stu64(xp1 + 2 * wv + 1, p1hi);
    }
    __syncthreads();  // drains the stores
    if (r == 0) stflag(flagsAp, 512);
  }
  if (r < 16) {  // final h in shb[*][pb]
    uint4 h0 = shb[0][pb][r];
    uint4 h1 = shb[1][pb][r];
    size_t ho0 = (size_t)(layer * 64 + b0) * 32;
    size_t ho1 = (size_t)(layer * 64 + b1) * 32;
    hidm[ho0 + 2 * r]     = ((unsigned long long)h0.y << 32) | h0.x;
    hidm[ho0 + 2 * r + 1] = ((unsigned long long)h0.w << 32) | h0.z;
    hidm[ho1 + 2 * r]     = ((unsigned long long)h1.y << 32) | h1.x;
    hidm[ho1 + 2 * r + 1] = ((unsigned long long)h1.w << 32) | h1.z;
  }
}

__global__ __launch_bounds__(1024, 4) void k_pipe(
    short* nbuf, unsigned long long* x0,
    const unsigned long long* __restrict__ wim,
    const unsigned long long* __restrict__ whm,
    const void* __restrict__ bih, const void* __restrict__ bhh,
    const int* __restrict__ flags, int* flagsA, int* flagsB,
    unsigned long long* __restrict__ hidm) {
  __shared__ __align__(16) uint4 shb[2][2][16];  // [bat][buf][16]
  int role = blockIdx.x % 3;  // interleave roles across XCDs
  int pair = blockIdx.x / 3;  // 0..31
  int r = threadIdx.x;
  int isf32 = flags[0];
  if (role == 0) {
    recur2<0>(shb, nbuf, whm, bih, bhh, isf32, 0, pair, r,
              x0, flagsA, flagsB, hidm);
  } else if (role == 1) {
    // ---- stage B: layer-1 input bit-GEMM, 2 batches, trails A ~3 steps ----
    // Loader lanes r<64: bat=r>>5, word=r&31 own x-word streams.
    // Invariants at top of step t: LDS [bat][t&1] = x_t; vnext = x_{t+1};
    // v2 = x_{t+2}; ncur0/1 = n_{t-1} (t>0, in registers).
    int b0 = 2 * pair, b1 = b0 + 1;
    const uint4* wrow = (const uint4*)(wim + (size_t)(1024 + r) * 32);
    int bat = r >> 5, word = r & 31;  // meaningful for r<64
    const unsigned long long* xsrc = x0 + (size_t)(b0 + bat) * 512 * 32;
    short* nout0 = nbuf + (size_t)b0 * 512 * 1024 + r;
    short* nout1 = nbuf + (size_t)b1 * 512 * 1024 + r;
    int* flagsAp = flagsA + pair * FLAG_STRIDE;
    int* flagsBp = flagsB + pair * FLAG_STRIDE;
    int fa = 0;
    unsigned long long vnext = 0, v2 = 0;
    if (r < 64) {  // prologue: x_0 -> buf[0]; x_1, x_2 -> regs
      while ((fa = ldflag(flagsAp)) < 1) {}
      ((unsigned long long*)(shb[bat][0]))[word] = ldu64(xsrc + word);
      while (fa < 2) { fa = ldflag(flagsAp); }
      vnext = ldu64(xsrc + 32 + word);
      while (fa < 3) { fa = ldflag(flagsAp); }
      v2 = ldu64(xsrc + 64 + word);
    }
    __syncthreads();
    short ncur0 = 0, ncur1 = 0;
    for (int t = 0; t < 512; t++) {
      // top of step: LDS-write x_{t+1}; store n_{t-1}; issue load x_{t+3}
      if (r < 64 && t < 511)
        ((unsigned long long*)(shb[bat][(t + 1) & 1]))[word] = vnext;
      if (t > 0) {
        sts16(nout0 + (size_t)(t - 1) * 1024, ncur0);
        sts16(nout1 + (size_t)(t - 1) * 1024, ncur1);
      }
      bool got = true;
      unsigned long long v3 = 0;
      if (r < 64 && t < 509) {  // distance-3 prefetch
        if (fa < t + 4) fa = ldflag(flagsAp);
        got = (fa >= t + 4);
        if (got) v3 = ldu64(xsrc + (size_t)(t + 3) * 32 + word);
      }
      const uint4* H0 = shb[0][t & 1];
      const uint4* H1 = shb[1][t & 1];
      DOT16X2(H0, H1, k0, k1, 0, 0);
      if (r < 64 && t < 509 && !got) {  // cold path: pipeline fill only
        while ((fa = ldflag(flagsAp)) < t + 4) {}
        v3 = ldu64(xsrc + (size_t)(t + 3) * 32 + word);
      }
      __syncthreads();   // drains n-stores + x-loads; LDS bufs visible
      if (r == 0 && t > 0) stflag(flagsBp, t);  // n[0..t-1] committed
      ncur0 = (short)k0;
      ncur1 = (short)k1;
      vnext = v2;
      v2 = v3;
    }
    // epilogue: commit n_511, publish full
    sts16(nout0 + (size_t)511 * 1024, ncur0);
    sts16(nout1 + (size_t)511 * 1024, ncur1);
    __syncthreads();
    if (r == 0) stflag(flagsBp, 512);
  } else {
    recur2<2>(shb, nbuf, whm, bih, bhh, isf32, 1, pair, r,
              (unsigned long long*)0, flagsA, flagsB, hidm);
  }
}

__global__ __launch_bounds__(64) void k_fc(const unsigned long long* __restrict__ hidm,
    const unsigned long long* __restrict__ fcm, const int* __restrict__ flags,
    void* __restrict__ out) {
  int isf32 = flags[0];
  int lb = blockIdx.x, lane = threadIdx.x;
  unsigned long long hp = 0, hz = 0;
  if (lane < 16) {
    hp = hidm[lb * 32 + 2 * lane];
    hz = hidm[lb * 32 + 2 * lane + 1];
  }
#pragma unroll
  for (int o = 0; o < 4; o++) {
    int k = 0;
    if (lane < 16) {
      unsigned long long wp = fcm[o * 32 + 2 * lane], wz = fcm[o * 32 + 2 * lane + 1];
      unsigned long long both = hz & wz;
      unsigned long long neg = both & (hp ^ wp);
      k = __popcll(both) - 2 * __popcll(neg);
    }
    for (int off = 8; off > 0; off >>= 1) k += __shfl_down(k, off);
    if (lane == 0) {
      float v = (float)((double)k * 0.1);
      if (isf32) ((float*)out)[lb * 4 + o] = v;
      else       ((unsigned short*)out)[lb * 4 + o] = f2bf(v);
    }
  }
}

extern "C" void kernel_launch(void* const* d_in, const int* in_sizes, int n_in,
                              void* d_out, int out_size, void* d_ws, size_t ws_size,
                              hipStream_t stream) {
  (void)in_sizes; (void)n_in; (void)out_size; (void)ws_size;
  const int* text = (const int*)d_in[0];
  // d_in[1] text_lengths: unused by the reference
  const void* emb = d_in[2];
  const void* Wih = d_in[3];
  const void* Whh = d_in[4];
  const void* bih = d_in[5];
  const void* bhh = d_in[6];
  const void* fcw = d_in[7];

  // workspace layout (~73 MB)
  char* ws = (char*)d_ws;
  int* flags = (int*)(ws);
  unsigned* mab = (unsigned*)(ws + 64);
  int* flagsA = (int*)(ws + 1024);   // 32 pair flags, stride 16 ints
  int* flagsB = (int*)(ws + 5120);   // 32 pair flags, stride 16 ints
  size_t off = 16384;
  unsigned long long* x0 = (unsigned long long*)(ws + off);  off += (size_t)32768 * 256;
  unsigned long long* wim = (unsigned long long*)(ws + off); off += (size_t)2048 * 256;
  unsigned long long* whm = (unsigned long long*)(ws + off); off += (size_t)2048 * 256;
  unsigned long long* fcm = (unsigned long long*)(ws + off); off += (size_t)4 * 256;
  unsigned long long* hidm = (unsigned long long*)(ws + off); off += (size_t)128 * 256;
  short* nbuf = (short*)(ws + off);                          off += (size_t)32768 * 1024 * 2;

  hipMemsetAsync(ws, 0, 16384, stream);  // flags, mab, flagsA, flagsB
  k_detect<<<256, 256, 0, stream>>>((const unsigned short*)emb, text, flags);
  k_maxabs<<<2048, 256, 0, stream>>>((const uint4*)emb, flags, mab);
  k_tern_rows<<<4100, 1024, 0, stream>>>(Wih, Whh, fcw, flags, wim, whm, fcm);
  k_embed<<<32768, 1024, 0, stream>>>(text, emb, flags, mab, x0);
  // layer-0 input gemm (x0 consumed; region then reused as layer-0 x-out)
  k_bitgemm<<<dim3(512, 4), 256, 0, stream>>>(x0, wim, nbuf);
  // fused pipeline: layer-0 recur || layer-1 bitgemm || layer-1 recur
  // 96 blocks = 32 pairs x 3 roles, 2 batches per block
  k_pipe<<<96, 1024, 0, stream>>>(nbuf, x0, wim, whm, bih, bhh, flags,
                                  flagsA, flagsB, hidm);
  k_fc<<<128, 64, 0, stream>>>(hidm, fcm, flags, d_out);
}

// Round 10
// 1590.127 us; speedup vs baseline: 5.0853x; 5.0853x over previous
//
#include <hip/hip_runtime.h>
#include <cstdint>
#include <cstddef>

// ---------------------------------------------------------------------------
// QRNN 2-bit forward, exact ternary-integer formulation.
// flags[0]=1 -> floats are f32 (else bf16); flags[1]=1 -> text is int64.
// Ternary vectors (len 1024) bit-packed as 32 u64: [2i]=plus, [2i+1]=nonzero.
// As uint4 i: (p.lo, p.hi, z.lo, z.hi) for elements 64i..64i+63.
// dot: both=hz&wz; neg=both&(hp^wp); k=popc(both)-2*popc(neg)
// Decision v = k*0.1+bias vs +-0.5 is monotone in k -> precomputed integer
// thresholds kp/km reproduce the f64 predicate bit-exactly.
//
// R-pipeline (k_pipe, 192 blocks = 64 A + 64 B + 64 C):
//   A = layer-0 recur (produces x_t), B = layer-1 input bit-GEMM (x_t -> n_t,
//   in-place into nbuf), C = layer-1 recur (consumes n_t).
// Fenceless handoff (R2, validated at 1177us): all cross-stage data
// stores/loads are RELAXED+AGENT (sc0 sc1 -> write/read-through the IC,
// never dirty in L2 => no wbl2). Flags are RELAXED agent stores issued
// AFTER __syncthreads() (barrier vmcnt(0) drain => all waves' IC stores
// visible first). Consumer data loads are control-dependent on observed
// flag values => ordered without acquire fences. Same-address flag stores
// separated by barriers. Dependency graph acyclic; 192 blocks x 16 waves
// @ 1 block/CU co-resident on 256 CUs => no deadlock.
//
// R10: WEIGHTS IN LDS (the store the register allocator can't touch).
// Verdict after 7 rounds: the backend pins these kernels at ~64 VGPRs and
// remats (R0-R3/R6-R8) or scratch-spills (R4/R5/R9) the 64 weight words at
// every hint. The per-step cost is the 256 KB/CU L2 re-stream (~2000-4400cy
// at 60-128 B/cy/CU link; VALU floor is only ~1400cy). Fix: cache 9 of 16
// weight quads per row in LDS (1024 rows x 37-dword pitch = 148 KB, staged
// once; pitch 37 => bank=(5r+i)%32, gcd(5,32)=1 => 2 lanes/bank = free).
// Stream only 7 quads (112 B/thread/step) from L2 => stream ~1500-1900cy,
// step ~2100-2700cy. Structure otherwise = V2 verbatim. Dynamic LDS 152 KB
// (1 block/CU) via hipFuncSetAttribute.
// ---------------------------------------------------------------------------

#define DRAIN_VMEM() asm volatile("s_waitcnt vmcnt(0)" ::: "memory")
#define FLAG_STRIDE 16  // one flag per 64 B to avoid line contention

#define WQ 9       // weight quads cached in LDS per row (of 16)
#define WPITCH 37  // dwords per LDS row: 36 data + 1 pad (conflict-free diag)
#define SMEM_BYTES (512 + 1024 * WPITCH * 4)  // shb(512B) + wlds(148KB)

static __device__ __forceinline__ float bf2f(unsigned short b) {
  return __uint_as_float(((unsigned)b) << 16);
}
static __device__ __forceinline__ unsigned short f2bf(float f) {
  unsigned u = __float_as_uint(f);
  u = (u + 0x7FFFu + ((u >> 16) & 1u)) >> 16;  // RNE
  return (unsigned short)u;
}
static __device__ __forceinline__ float loadw(const void* p, size_t i, int isf32) {
  return isf32 ? ((const float*)p)[i] : bf2f(((const unsigned short*)p)[i]);
}

__global__ __launch_bounds__(256) void k_detect(const unsigned short* __restrict__ embu,
                                                const int* __restrict__ text,
                                                int* __restrict__ flags) {
  int i = blockIdx.x * 256 + threadIdx.x;  // 65536 u16 samples: valid in either layout
  unsigned e = (embu[i] >> 7) & 0xFFu;     // bf16-view exponent field
  unsigned long long b = __ballot(e >= 127u);
  if ((threadIdx.x & 63) == 0 && b) atomicOr(&flags[0], 1);
  if (blockIdx.x == 0 && threadIdx.x == 0) {
    int allz = 1;
    for (int j = 0; j < 32; j++)
      if (text[2 * j + 1] != 0) allz = 0;   // first 256 B: valid in either layout
    flags[1] = allz;
  }
}

// vectorized max|emb|
__global__ __launch_bounds__(256) void k_maxabs(const uint4* __restrict__ w,
                                                const int* __restrict__ flags,
                                                unsigned* __restrict__ out) {
  int isf32 = flags[0];
  int n16 = isf32 ? 7680000 : 3840000;  // 30720000 elems / (4 or 8 per uint4)
  float mf = 0.f;
  unsigned mb = 0;
  int i = blockIdx.x * blockDim.x + threadIdx.x;
  int stride = gridDim.x * blockDim.x;
  if (isf32) {
    for (; i < n16; i += stride) {
      uint4 v = w[i];
      mf = fmaxf(mf, fabsf(__uint_as_float(v.x)));
      mf = fmaxf(mf, fabsf(__uint_as_float(v.y)));
      mf = fmaxf(mf, fabsf(__uint_as_float(v.z)));
      mf = fmaxf(mf, fabsf(__uint_as_float(v.w)));
    }
  } else {
    for (; i < n16; i += stride) {
      uint4 v = w[i];
      unsigned a;
      a = v.x & 0x7FFF7FFFu; mb = max(mb, a & 0xFFFFu); mb = max(mb, a >> 16);
      a = v.y & 0x7FFF7FFFu; mb = max(mb, a & 0xFFFFu); mb = max(mb, a >> 16);
      a = v.z & 0x7FFF7FFFu; mb = max(mb, a & 0xFFFFu); mb = max(mb, a >> 16);
      a = v.w & 0x7FFF7FFFu; mb = max(mb, a & 0xFFFFu); mb = max(mb, a >> 16);
    }
    mf = bf2f((unsigned short)mb);
  }
  for (int off = 32; off > 0; off >>= 1) mf = fmaxf(mf, __shfl_down(mf, off));
  __shared__ float red[4];
  if ((threadIdx.x & 63) == 0) red[threadIdx.x >> 6] = mf;
  __syncthreads();
  if (threadIdx.x == 0) {
    float b = fmaxf(fmaxf(red[0], red[1]), fmaxf(red[2], red[3]));
    atomicMax(out, __float_as_uint(b));  // b >= 0: bit pattern order-monotone
  }
}

__global__ __launch_bounds__(1024) void k_tern_rows(
    const void* __restrict__ Wih, const void* __restrict__ Whh,
    const void* __restrict__ fcw, const int* __restrict__ flags,
    unsigned long long* __restrict__ wim, unsigned long long* __restrict__ whm,
    unsigned long long* __restrict__ fcm) {
  int isf32 = flags[0];
  int b = blockIdx.x;  // 0..4099
  const void* src;
  size_t rowoff;
  unsigned long long* dst;
  if (b < 2048)      { src = Wih; rowoff = (size_t)b * 1024; dst = wim + (size_t)b * 32; }
  else if (b < 4096) { int r = b - 2048; src = Whh; rowoff = (size_t)r * 1024; dst = whm + (size_t)r * 32; }
  else               { int r = b - 4096; src = fcw; rowoff = (size_t)r * 1024; dst = fcm + (size_t)r * 32; }
  double w = (double)loadw(src, rowoff + threadIdx.x, isf32);
  unsigned long long bp = __ballot(w > 0.05);   // THR*W_SCALE, exact f64
  unsigned long long bm = __ballot(w < -0.05);
  if ((threadIdx.x & 63) == 0) {
    int wv = threadIdx.x >> 6;
    dst[2 * wv] = bp;
    dst[2 * wv + 1] = bp | bm;
  }
}

__global__ __launch_bounds__(1024) void k_embed(const int* __restrict__ text,
    const void* __restrict__ emb, const int* __restrict__ flags,
    const unsigned* __restrict__ mab, unsigned long long* __restrict__ x0) {
  int isf32 = flags[0], i64 = flags[1];
  int bt = blockIdx.x;
  long long tok = i64 ? ((const long long*)text)[bt] : (long long)text[bt];
  double ma = (double)__uint_as_float(*mab);
  float s = (float)exp2(ceil(log2(ma)));           // pow-2 scale (int_max = 1)
  float inv_s = 1.0f / s;                          // exact (pow-2)
  float w = loadw(emb, (size_t)tok * 1024 + threadIdx.x, isf32);
  float q = rintf(w * inv_s);                      // exact mul, half-even
  q = fminf(fmaxf(q, -2.0f), 1.0f);                // clip [-2, 1] (bw = 2)
  float val = q * s;                               // exact
  int code = (val > 0.5f) ? 1 : ((val < -0.5f) ? -1 : 0);
  unsigned long long bp = __ballot(code == 1);
  unsigned long long bm = __ballot(code == -1);
  if ((threadIdx.x & 63) == 0) {
    int wv = threadIdx.x >> 6;
    x0[(size_t)bt * 32 + 2 * wv] = bp;
    x0[(size_t)bt * 32 + 2 * wv + 1] = bp | bm;
  }
}

// ---- bit-GEMM (layer-0 pre-pass): n[bt][r] = <x_row[bt], Wi_row[r]> -------
__global__ __launch_bounds__(256, 4) void k_bitgemm(const unsigned long long* __restrict__ xm,
    const unsigned long long* __restrict__ wim, short* __restrict__ nbuf) {
  __shared__ __align__(16) uint4 lx[64 * 16];  // [bt][i] = (p.lo,p.hi,z.lo,z.hi)
  __shared__ unsigned any[64];
  int tid = threadIdx.x;
  int bt0 = blockIdx.x * 64;
  int r = blockIdx.y * 256 + tid;
  unsigned wplo[16], wphi[16], wzlo[16], wzhi[16];
  const uint4* wrow = (const uint4*)(wim + (size_t)r * 32);
#pragma unroll
  for (int i = 0; i < 16; i++) {
    uint4 w4 = wrow[i];
    wplo[i] = w4.x; wphi[i] = w4.y; wzlo[i] = w4.z; wzhi[i] = w4.w;
  }
  if (tid < 64) any[tid] = 0;
  __syncthreads();
  unsigned accor = 0;
#pragma unroll
  for (int i = 0; i < 4; i++) {
    int idx = tid * 4 + i;  // 0..1023 uint4 slots, straight copy
    uint4 v = ((const uint4*)(xm + (size_t)bt0 * 32))[idx];
    lx[idx] = v;
    accor |= v.z | v.w;  // nonzero-mask halves
  }
  if (accor) atomicOr(&any[tid >> 2], 1u);  // 4 threads per bt row
  __syncthreads();
  for (int bt = 0; bt < 64; bt++) {
    int k = 0;
    if (any[bt]) {
      const uint4* hx = lx + bt * 16;
      int sb = 0, sn = 0;
#pragma unroll
      for (int i = 0; i < 16; i++) {
        uint4 h = hx[i];  // broadcast ds_read_b128
        unsigned blo = h.z & wzlo[i];
        unsigned bhi = h.w & wzhi[i];
        unsigned nlo = (h.x ^ wplo[i]) & blo;
        unsigned nhi = (h.y ^ wphi[i]) & bhi;
        sb += __popc(blo) + __popc(bhi);
        sn += __popc(nlo) + __popc(nhi);
      }
      k = sb - 2 * sn;
    }
    nbuf[(size_t)(bt0 + bt) * 1024 + r] = (short)k;
  }
}

// ---- fused 3-stage pipeline ----------------------------------------------

static __device__ __forceinline__ int ldflag(const int* p) {
  return __hip_atomic_load(p, __ATOMIC_RELAXED, __HIP_MEMORY_SCOPE_AGENT);
}
static __device__ __forceinline__ void stflag(int* p, int v) {
  __hip_atomic_store(p, v, __ATOMIC_RELAXED, __HIP_MEMORY_SCOPE_AGENT);
}
static __device__ __forceinline__ unsigned long long ldu64(const unsigned long long* p) {
  return __hip_atomic_load(p, __ATOMIC_RELAXED, __HIP_MEMORY_SCOPE_AGENT);
}
static __device__ __forceinline__ int lds16(const short* p) {
  return (int)__hip_atomic_load(p, __ATOMIC_RELAXED, __HIP_MEMORY_SCOPE_AGENT);
}

// stage WQ quads of this thread's weight row into LDS (diagonal pitch)
static __device__ __forceinline__ void stage_wlds(unsigned* wlds, int r,
                                                  const uint4* wrow) {
  int base = r * WPITCH;
#pragma unroll
  for (int i = 0; i < WQ; i++) {
    uint4 w4 = wrow[i];
    wlds[base + 4 * i]     = w4.x;
    wlds[base + 4 * i + 1] = w4.y;
    wlds[base + 4 * i + 2] = w4.z;
    wlds[base + 4 * i + 3] = w4.w;
  }
}

// one dot term vs LDS-cached quad i (conflict-free b32 reads)
#define DOT_LDS(I)                                                         \
  {                                                                        \
    uint4 h = Hq[I];                                                       \
    unsigned wx = wlds[wb + 4 * (I)], wy = wlds[wb + 4 * (I) + 1];         \
    unsigned wz = wlds[wb + 4 * (I) + 2], ww = wlds[wb + 4 * (I) + 3];     \
    unsigned blo = h.z & wz;                                               \
    unsigned bhi = h.w & ww;                                               \
    unsigned nlo = (h.x ^ wx) & blo;                                       \
    unsigned nhi = (h.y ^ wy) & bhi;                                       \
    sb += __popc(blo) + __popc(bhi);                                       \
    sn += __popc(nlo) + __popc(nhi);                                       \
  }

// one dot term vs streamed quad i (L2; only 16-WQ=7 in flight)
#define DOT_STREAM(I)                                                      \
  {                                                                        \
    uint4 h = Hq[I];                                                       \
    uint4 w4 = wrow[I];                                                    \
    unsigned blo = h.z & w4.z;                                             \
    unsigned bhi = h.w & w4.w;                                             \
    unsigned nlo = (h.x ^ w4.x) & blo;                                     \
    unsigned nhi = (h.y ^ w4.y) & bhi;                                     \
    sb += __popc(blo) + __popc(bhi);                                       \
    sn += __popc(nlo) + __popc(nhi);                                       \
  }

// ROLE 0 = layer-0 recur (producer of x_t); ROLE 2 = layer-1 recur (consumer)
template <int ROLE>
static __device__ __forceinline__ void recur_stage(
    uint4 (*shb)[16], unsigned* wlds, const short* nbuf,
    const unsigned long long* __restrict__ whm,
    const void* __restrict__ bih, const void* __restrict__ bhh,
    int isf32, int layer, int b, int r,
    unsigned long long* xrow,              // ROLE 0 only
    int* flagsA, int* flagsB,
    unsigned long long* __restrict__ hidm) {
  const uint4* wrow = (const uint4*)(whm + (size_t)(layer * 1024 + r) * 32);
  stage_wlds(wlds, r, wrow);
  size_t boff = (size_t)layer * 1024 + r;
  double bias = (double)loadw(bih, boff, isf32) + (double)loadw(bhh, boff, isf32);
  // exact integer thresholds reproducing the f64 predicate
  int kp = (int)ceil((0.5 - bias) * 10.0);
  while ((double)kp * 0.1 + bias <= 0.5) kp++;
  while ((double)(kp - 1) * 0.1 + bias > 0.5) kp--;
  int km = (int)floor((-0.5 - bias) * 10.0);
  while ((double)km * 0.1 + bias >= -0.5) km--;
  while ((double)(km + 1) * 0.1 + bias < -0.5) km++;

  if (r < 32) ((unsigned long long*)shb)[r] = 0;  // zero buffer 0
  const short* nrow = nbuf + (size_t)b * 512 * 1024 + r;
  int wv = r >> 6;
  int wb = r * WPITCH;
  bool l0 = (r & 63) == 0;
  int fl = 0;   // ROLE 2: cached flagsB
  int* flagsAp = flagsA + b * FLAG_STRIDE;
  int* flagsBp = flagsB + b * FLAG_STRIDE;
  int nin;
  if (ROLE == 0) {
    nin = (int)nrow[0];  // t = 0 preload (pre-pass bitgemm data: plain load ok)
  } else {
    while ((fl = ldflag(flagsBp)) < 1) {}
    // data load control-dependent on flag value => ordered, no acquire needed
    nin = lds16(nrow);
  }
  __syncthreads();  // staging writes + shb zero visible; nin ready
  int pb = 0;
  unsigned long long plo = 0, phi = 0;  // ROLE 0, l0 lanes: deferred x words
  for (int t = 0; t < 512; t++) {
    if (ROLE == 0) {
      // deferred store of x_{t-1}: IC ack hides under this step's dot
      if (l0 && t > 0) {
        __hip_atomic_store(xrow + (size_t)(t - 1) * 32 + 2 * wv, plo,
                           __ATOMIC_RELAXED, __HIP_MEMORY_SCOPE_AGENT);
        __hip_atomic_store(xrow + (size_t)(t - 1) * 32 + 2 * wv + 1, phi,
                           __ATOMIC_RELAXED, __HIP_MEMORY_SCOPE_AGENT);
      }
    } else {
      if (t < 511 && fl < t + 2)  // one non-spin refresh; consumed mid-dot
        fl = ldflag(flagsBp);
    }
    const uint4* Hq = shb[pb];
    int sb = 0, sn = 0;
    DOT_LDS(0) DOT_LDS(1) DOT_LDS(2) DOT_LDS(3)
    DOT_LDS(4) DOT_LDS(5) DOT_LDS(6) DOT_LDS(7)
    // mid-dot: prefetch next-step input so its latency hides under the rest
    int nin_next = 0;
    bool got = true;
    if (ROLE == 0) {
      if (t < 511) nin_next = (int)nrow[(size_t)(t + 1) * 1024];
    } else if (t < 511) {
      got = (fl >= t + 2);
      if (got)
        nin_next = lds16(nrow + (size_t)(t + 1) * 1024);
    }
    DOT_LDS(8)
    DOT_STREAM(9)  DOT_STREAM(10) DOT_STREAM(11) DOT_STREAM(12)
    DOT_STREAM(13) DOT_STREAM(14) DOT_STREAM(15)
    int k = nin + sb - 2 * sn;
    unsigned long long bp = __ballot(k >= kp);
    unsigned long long bm = __ballot(k <= km);
    unsigned long long bz = bp | bm;
    if (l0) {
      uint4 o;
      o.x = (unsigned)bp; o.y = (unsigned)(bp >> 32);
      o.z = (unsigned)bz; o.w = (unsigned)(bz >> 32);
      shb[pb ^ 1][wv] = o;
      plo = bp; phi = bz;  // defer global store to next step
    }
    if (ROLE == 2 && !got && t < 511) {  // cold path: pipeline fill only
      while ((fl = ldflag(flagsBp)) < t + 2) {}
      nin_next = lds16(nrow + (size_t)(t + 1) * 1024);
    }
    if (ROLE == 0) DRAIN_VMEM();  // per-wave: x-stores IC-acked before barrier
    __syncthreads();
    // publish AFTER barrier: all waves' stores of x[<=t-1] globally visible.
    if (ROLE == 0 && r == 0 && t > 0)
      stflag(flagsAp, t);
    pb ^= 1;
    nin = nin_next;
  }
  if (ROLE == 0) {  // commit x[511], then final publish
    if (l0) {
      __hip_atomic_store(xrow + (size_t)511 * 32 + 2 * wv, plo,
                         __ATOMIC_RELAXED, __HIP_MEMORY_SCOPE_AGENT);
      __hip_atomic_store(xrow + (size_t)511 * 32 + 2 * wv + 1, phi,
                         __ATOMIC_RELAXED, __HIP_MEMORY_SCOPE_AGENT);
    }
    DRAIN_VMEM();
    __syncthreads();
    if (r == 0) stflag(flagsAp, 512);
  }
  if (r < 16) {  // final h is in shb[pb]
    uint4 h = shb[pb][r];
    size_t ho = (size_t)(layer * 64 + b) * 32;
    hidm[ho + 2 * r]     = ((unsigned long long)h.y << 32) | h.x;
    hidm[ho + 2 * r + 1] = ((unsigned long long)h.w << 32) | h.z;
  }
}

__global__ __launch_bounds__(1024, 4) void k_pipe(
    short* nbuf, unsigned long long* x0,
    const unsigned long long* __restrict__ wim,
    const unsigned long long* __restrict__ whm,
    const void* __restrict__ bih, const void* __restrict__ bhh,
    const int* __restrict__ flags, int* flagsA, int* flagsB,
    unsigned long long* __restrict__ hidm) {
  extern __shared__ __align__(16) unsigned char smem[];
  uint4 (*shb)[16] = (uint4 (*)[16])smem;        // 512 B
  unsigned* wlds = (unsigned*)(smem + 512);      // 1024 * WPITCH dwords
  int role = blockIdx.x % 3;  // interleave roles across XCDs
  int b = blockIdx.x / 3;
  int r = threadIdx.x;
  int isf32 = flags[0];
  if (role == 0) {
    recur_stage<0>(shb, wlds, nbuf, whm, bih, bhh, isf32, 0, b, r,
                   x0 + (size_t)b * 512 * 32, flagsA, flagsB, hidm);
  } else if (role == 1) {
    // ---- stage B: layer-1 input bit-GEMM, trailing A by ~2 steps ----------
    const uint4* wrow = (const uint4*)(wim + (size_t)(1024 + r) * 32);
    stage_wlds(wlds, r, wrow);
    const unsigned long long* xsrc = x0 + (size_t)b * 512 * 32;
    short* nout = nbuf + (size_t)b * 512 * 1024 + r;
    int* flagsAp = flagsA + b * FLAG_STRIDE;
    int* flagsBp = flagsB + b * FLAG_STRIDE;
    int wb = r * WPITCH;
    int fa = 0;
    unsigned long long vcur = 0;
    if (r < 32) {  // prologue: x[0] (flag spin by loader half-wave only)
      while ((fa = ldflag(flagsAp)) < 1) {}
      vcur = ldu64(xsrc + r);
    }
    __syncthreads();  // staging writes visible
    for (int t = 0; t < 512; t++) {
      if (r < 32) ((unsigned long long*)(shb[t & 1]))[r] = vcur;
      __syncthreads();
      // issue next x load early: IC latency hides under the dot
      bool got = false;
      unsigned long long vnext = 0;
      if (r < 32 && t < 511) {
        if (fa < t + 2) fa = ldflag(flagsAp);
        if (fa >= t + 2) {
          vnext = ldu64(xsrc + (size_t)(t + 1) * 32 + r);
          got = true;
        }
      }
      const uint4* Hq = shb[t & 1];
      int sb = 0, sn = 0;
      DOT_LDS(0) DOT_LDS(1) DOT_LDS(2)  DOT_LDS(3)
      DOT_LDS(4) DOT_LDS(5) DOT_LDS(6)  DOT_LDS(7)
      DOT_LDS(8)
      DOT_STREAM(9)  DOT_STREAM(10) DOT_STREAM(11) DOT_STREAM(12)
      DOT_STREAM(13) DOT_STREAM(14) DOT_STREAM(15)
      // write-through to IC (sc0 sc1): no dirty L2 line, no wbl2 ever
      __hip_atomic_store(nout + (size_t)t * 1024, (short)(sb - 2 * sn),
                         __ATOMIC_RELAXED, __HIP_MEMORY_SCOPE_AGENT);
      if (r < 32 && t < 511 && !got) {  // cold path: pipeline fill only
        while ((fa = ldflag(flagsAp)) < t + 2) {}
        vnext = ldu64(xsrc + (size_t)(t + 1) * 32 + r);
      }
      DRAIN_VMEM();      // per-wave: n-stores IC-acked before barrier
      __syncthreads();
      if (r == 0) stflag(flagsBp, t + 1);  // after barrier
      vcur = vnext;
    }
  } else {
    recur_stage<2>(shb, wlds, nbuf, whm, bih, bhh, isf32, 1, b, r,
                   (unsigned long long*)0, flagsA, flagsB, hidm);
  }
}

__global__ __launch_bounds__(64) void k_fc(const unsigned long long* __restrict__ hidm,
    const unsigned long long* __restrict__ fcm, const int* __restrict__ flags,
    void* __restrict__ out) {
  int isf32 = flags[0];
  int lb = blockIdx.x, lane = threadIdx.x;
  unsigned long long hp = 0, hz = 0;
  if (lane < 16) {
    hp = hidm[lb * 32 + 2 * lane];
    hz = hidm[lb * 32 + 2 * lane + 1];
  }
#pragma unroll
  for (int o = 0; o < 4; o++) {
    int k = 0;
    if (lane < 16) {
      unsigned long long wp = fcm[o * 32 + 2 * lane], wz = fcm[o * 32 + 2 * lane + 1];
      unsigned long long both = hz & wz;
      unsigned long long neg = both & (hp ^ wp);
      k = __popcll(both) - 2 * __popcll(neg);
    }
    for (int off = 8; off > 0; off >>= 1) k += __shfl_down(k, off);
    if (lane == 0) {
      float v = (float)((double)k * 0.1);
      if (isf32) ((float*)out)[lb * 4 + o] = v;
      else       ((unsigned short*)out)[lb * 4 + o] = f2bf(v);
    }
  }
}

extern "C" void kernel_launch(void* const* d_in, const int* in_sizes, int n_in,
                              void* d_out, int out_size, void* d_ws, size_t ws_size,
                              hipStream_t stream) {
  (void)in_sizes; (void)n_in; (void)out_size; (void)ws_size;
  const int* text = (const int*)d_in[0];
  // d_in[1] text_lengths: unused by the reference
  const void* emb = d_in[2];
  const void* Wih = d_in[3];
  const void* Whh = d_in[4];
  const void* bih = d_in[5];
  const void* bhh = d_in[6];
  const void* fcw = d_in[7];

  // one-time: allow 152 KB dynamic LDS on k_pipe (HW limit 160 KB/CU)
  static bool smem_attr_set = false;
  if (!smem_attr_set) {
    hipFuncSetAttribute(reinterpret_cast<const void*>(&k_pipe),
                        hipFuncAttributeMaxDynamicSharedMemorySize, SMEM_BYTES);
    smem_attr_set = true;
  }

  // workspace layout (~73 MB)
  char* ws = (char*)d_ws;
  int* flags = (int*)(ws);
  unsigned* mab = (unsigned*)(ws + 64);
  int* flagsA = (int*)(ws + 1024);   // 64 flags, stride 16 ints (4 KB)
  int* flagsB = (int*)(ws + 5120);   // 64 flags, stride 16 ints (4 KB)
  size_t off = 16384;
  unsigned long long* x0 = (unsigned long long*)(ws + off);  off += (size_t)32768 * 256;
  unsigned long long* wim = (unsigned long long*)(ws + off); off += (size_t)2048 * 256;
  unsigned long long* whm = (unsigned long long*)(ws + off); off += (size_t)2048 * 256;
  unsigned long long* fcm = (unsigned long long*)(ws + off); off += (size_t)4 * 256;
  unsigned long long* hidm = (unsigned long long*)(ws + off); off += (size_t)128 * 256;
  short* nbuf = (short*)(ws + off);                          off += (size_t)32768 * 1024 * 2;

  hipMemsetAsync(ws, 0, 16384, stream);  // flags, mab, flagsA, flagsB
  k_detect<<<256, 256, 0, stream>>>((const unsigned short*)emb, text, flags);
  k_maxabs<<<2048, 256, 0, stream>>>((const uint4*)emb, flags, mab);
  k_tern_rows<<<4100, 1024, 0, stream>>>(Wih, Whh, fcw, flags, wim, whm, fcm);
  k_embed<<<32768, 1024, 0, stream>>>(text, emb, flags, mab, x0);
  // layer-0 input gemm (x0 consumed; region then reused as layer-0 x-out)
  k_bitgemm<<<dim3(512, 4), 256, 0, stream>>>(x0, wim, nbuf);
  // fused pipeline: layer-0 recur || layer-1 bitgemm || layer-1 recur
  k_pipe<<<192, 1024, SMEM_BYTES, stream>>>(nbuf, x0, wim, whm, bih, bhh, flags,
                                            flagsA, flagsB, hidm);
  k_fc<<<128, 64, 0, stream>>>(hidm, fcm, flags, d_out);
}